// Round 8
// baseline (359.755 us; speedup 1.0000x reference)
//
#include <hip/hip_runtime.h>

#define S_LEN 2048
#define D_MODEL 1024
#define NH 16
#define DH 64

typedef __bf16 bf16x8 __attribute__((ext_vector_type(8)));
typedef __bf16 bf16x4 __attribute__((ext_vector_type(4)));
typedef float f32x4 __attribute__((ext_vector_type(4)));

__device__ __forceinline__ unsigned short f2bf(float f) {
  unsigned int x = __float_as_uint(f);
  x += 0x7fffu + ((x >> 16) & 1u);  // RNE
  return (unsigned short)(x >> 16);
}

__device__ __forceinline__ bf16x4 cvt4(f32x4 v) {
  return __builtin_convertvector(v, bf16x4);
}

__device__ __forceinline__ float exp2raw(float x) {
#if __has_builtin(__builtin_amdgcn_exp2f)
  return __builtin_amdgcn_exp2f(x);
#else
  return exp2f(x);
#endif
}

__device__ __forceinline__ f32x4 mfma16(bf16x8 a, bf16x8 b, f32x4 c) {
  return __builtin_amdgcn_mfma_f32_16x16x32_bf16(a, b, c, 0, 0, 0);
}

// ---- fused prep: pack mask bits (blocks 0..32767) + fp32->bf16 convert ----
__global__ __launch_bounds__(256) void prep_kernel(
    const float* __restrict__ q, const float* __restrict__ wq,
    const float* __restrict__ wk, const float* __restrict__ wv,
    const float* __restrict__ wo, const int* __restrict__ mask,
    unsigned short* __restrict__ qbf, unsigned short* __restrict__ wbf,
    unsigned long long* __restrict__ bits) {
  const int bx = blockIdx.x;
  if (bx < 32768) {  // pack mask: 1 bit per (b,q,key), lane i <-> bit i
    int i = bx * 256 + threadIdx.x;
    unsigned long long bal = __ballot(mask[i] != 0);
    if ((threadIdx.x & 63) == 0) bits[i >> 6] = bal;
  } else {  // convert 8 floats per thread
    const long t = (long)(bx - 32768) * 256 + threadIdx.x;
    const float* src;
    unsigned short* dst;
    long e;
    if (t < 524288) { src = q; dst = qbf; e = t * 8; }
    else {
      long u = t - 524288;
      int wi = (int)(u >> 17);
      e = (u & 131071) * 8;
      src = wi == 0 ? wq : wi == 1 ? wk : wi == 2 ? wv : wo;
      dst = wbf + (long)wi * 1048576;
    }
    float4 a = *(const float4*)(src + e);
    float4 b = *(const float4*)(src + e + 4);
    ushort4 p0 = {f2bf(a.x), f2bf(a.y), f2bf(a.z), f2bf(a.w)};
    ushort4 p1 = {f2bf(b.x), f2bf(b.y), f2bf(b.z), f2bf(b.w)};
    *(ushort4*)(dst + e) = p0;
    *(ushort4*)(dst + e + 4) = p1;
  }
}

// ---- fused QKV GEMM, reg-prefetch double-buffered K-loop ----
// C = A(4096x1024) @ [Wq;Wk;Wv](3072x1024)^T; 128x128 tile, BK=64.
// Stage via global_load->VGPR->ds_write: barrier drains lgkm only; next
// tile's loads issued after the barrier stay in flight across compute.
__global__ __launch_bounds__(256, 2) void gemm_qkv(
    const unsigned short* __restrict__ A, const unsigned short* __restrict__ W3,
    unsigned short* __restrict__ qb, unsigned short* __restrict__ kb,
    unsigned short* __restrict__ vt, float qscale) {
  __shared__ unsigned short As[2][128 * 64];  // 32 KB
  __shared__ unsigned short Bs[2][128 * 64];  // 32 KB
  const int tid = threadIdx.x, lane = tid & 63, wid = tid >> 6;
  const int wm = wid >> 1, wn = wid & 1;
  const int quad = lane >> 4, c = lane & 15, cx = c & 7;
  const int nG = blockIdx.x * 128;
  const int wi = nG >> 10, nn0 = nG & 1023;
  const int m0 = blockIdx.y * 128;
  const unsigned short* Bsrc = W3 + (size_t)wi * 1048576;
  const int srow = lane >> 3;
  const int schk = ((lane & 7) ^ srow) * 8;  // XOR-swizzled global chunk
  const unsigned short* ag = A + (size_t)(m0 + wid * 32 + srow) * 1024 + schk;
  const unsigned short* bg =
      Bsrc + (size_t)(nn0 + wid * 32 + srow) * 1024 + schk;
  f32x4 acc[4][4] = {};
  uint4 ra[4], rb[4];
#pragma unroll
  for (int i = 0; i < 4; ++i) {
    ra[i] = *(const uint4*)(ag + (size_t)(i * 8) * 1024);
    rb[i] = *(const uint4*)(bg + (size_t)(i * 8) * 1024);
  }
  for (int kk = 0; kk < 1024; kk += 64) {
    const int pb = (kk >> 6) & 1;
    unsigned short* da = &As[pb][(wid * 32) * 64] + lane * 8;
    unsigned short* db = &Bs[pb][(wid * 32) * 64] + lane * 8;
#pragma unroll
    for (int i = 0; i < 4; ++i) {
      *(uint4*)(da + i * 512) = ra[i];
      *(uint4*)(db + i * 512) = rb[i];
    }
    __syncthreads();
    if (kk + 64 < 1024) {
#pragma unroll
      for (int i = 0; i < 4; ++i) {
        ra[i] = *(const uint4*)(ag + (size_t)(i * 8) * 1024 + kk + 64);
        rb[i] = *(const uint4*)(bg + (size_t)(i * 8) * 1024 + kk + 64);
      }
    }
#pragma unroll
    for (int kc = 0; kc < 2; ++kc) {
      bf16x8 a[4], b[4];
#pragma unroll
      for (int mt = 0; mt < 4; ++mt)
        a[mt] = *(const bf16x8*)(
            &As[pb][(wm * 64 + mt * 16 + c) * 64 + ((kc * 4 + quad) ^ cx) * 8]);
#pragma unroll
      for (int nt = 0; nt < 4; ++nt)
        b[nt] = *(const bf16x8*)(
            &Bs[pb][(wn * 64 + nt * 16 + c) * 64 + ((kc * 4 + quad) ^ cx) * 8]);
#pragma unroll
      for (int mt = 0; mt < 4; ++mt)
#pragma unroll
        for (int nt = 0; nt < 4; ++nt)
          acc[mt][nt] = mfma16(a[mt], b[nt], acc[mt][nt]);
    }
    // no trailing barrier: double buffer + the single barrier above suffice
  }
#pragma unroll
  for (int mt = 0; mt < 4; ++mt) {
#pragma unroll
    for (int nt = 0; nt < 4; ++nt) {
      const int mb = m0 + wm * 64 + mt * 16 + quad * 4;
      const int n = nn0 + wn * 64 + nt * 16 + c;
      const int hh = n >> 6, d = n & 63;
      const int bb = mb >> 11, ss = mb & 2047;
      if (wi == 0) {
#pragma unroll
        for (int r = 0; r < 4; ++r)
          qb[(size_t)((bb * NH + hh) * S_LEN + ss + r) * DH + d] =
              f2bf(acc[mt][nt][r] * qscale);
      } else if (wi == 1) {
#pragma unroll
        for (int r = 0; r < 4; ++r)
          kb[(size_t)((bb * NH + hh) * S_LEN + ss + r) * DH + d] =
              f2bf(acc[mt][nt][r]);
      } else {  // V^T: 4 regs = 4 consecutive s
        *(bf16x4*)(vt + (size_t)((bb * NH + hh) * DH + d) * S_LEN + ss) =
            cvt4(acc[mt][nt]);
      }
    }
  }
}

// ---- O projection, same reg-prefetch dbuf structure; fp32 out + bias ----
__global__ __launch_bounds__(256, 2) void gemm_out(
    const unsigned short* __restrict__ A, const unsigned short* __restrict__ W,
    float* __restrict__ out, const float* __restrict__ bias) {
  __shared__ unsigned short As[2][128 * 64];  // 32 KB
  __shared__ unsigned short Bs[2][64 * 64];   // 16 KB
  const int tid = threadIdx.x, lane = tid & 63, wid = tid >> 6;
  const int wm = wid >> 1, wn = wid & 1;
  const int quad = lane >> 4, c = lane & 15, cx = c & 7;
  const int n0 = blockIdx.x * 64, m0 = blockIdx.y * 128;
  const int srow = lane >> 3;
  const int schk = ((lane & 7) ^ srow) * 8;
  const unsigned short* ag = A + (size_t)(m0 + wid * 32 + srow) * 1024 + schk;
  const unsigned short* bg = W + (size_t)(n0 + wid * 16 + srow) * 1024 + schk;
  f32x4 acc[4][2] = {};
  uint4 ra[4], rb[2];
#pragma unroll
  for (int i = 0; i < 4; ++i)
    ra[i] = *(const uint4*)(ag + (size_t)(i * 8) * 1024);
#pragma unroll
  for (int i = 0; i < 2; ++i)
    rb[i] = *(const uint4*)(bg + (size_t)(i * 8) * 1024);
  for (int kk = 0; kk < 1024; kk += 64) {
    const int pb = (kk >> 6) & 1;
    unsigned short* da = &As[pb][(wid * 32) * 64] + lane * 8;
    unsigned short* db = &Bs[pb][(wid * 16) * 64] + lane * 8;
#pragma unroll
    for (int i = 0; i < 4; ++i) *(uint4*)(da + i * 512) = ra[i];
#pragma unroll
    for (int i = 0; i < 2; ++i) *(uint4*)(db + i * 512) = rb[i];
    __syncthreads();
    if (kk + 64 < 1024) {
#pragma unroll
      for (int i = 0; i < 4; ++i)
        ra[i] = *(const uint4*)(ag + (size_t)(i * 8) * 1024 + kk + 64);
#pragma unroll
      for (int i = 0; i < 2; ++i)
        rb[i] = *(const uint4*)(bg + (size_t)(i * 8) * 1024 + kk + 64);
    }
#pragma unroll
    for (int kc = 0; kc < 2; ++kc) {
      bf16x8 a[4], b[2];
#pragma unroll
      for (int mt = 0; mt < 4; ++mt)
        a[mt] = *(const bf16x8*)(
            &As[pb][(wm * 64 + mt * 16 + c) * 64 + ((kc * 4 + quad) ^ cx) * 8]);
#pragma unroll
      for (int nt = 0; nt < 2; ++nt)
        b[nt] = *(const bf16x8*)(
            &Bs[pb][(wn * 32 + nt * 16 + c) * 64 + ((kc * 4 + quad) ^ cx) * 8]);
#pragma unroll
      for (int mt = 0; mt < 4; ++mt)
#pragma unroll
        for (int nt = 0; nt < 2; ++nt)
          acc[mt][nt] = mfma16(a[mt], b[nt], acc[mt][nt]);
    }
  }
#pragma unroll
  for (int mt = 0; mt < 4; ++mt) {
#pragma unroll
    for (int nt = 0; nt < 2; ++nt) {
      const int mb = m0 + wm * 64 + mt * 16 + quad * 4;
      const int n = n0 + wn * 32 + nt * 16 + c;
      const float bv = bias[n];
#pragma unroll
      for (int r = 0; r < 4; ++r)
        out[(size_t)(mb + r) * D_MODEL + n] = acc[mt][nt][r] + bv;
    }
  }
}

// ---- flash attention, static-max softmax, 64q/wave, reg-prefetch dbuf ----
// block = (head, 128 q, batch); 4 waves = 2 qwaves(64q) x 2 key-halves.
// KV double-buffered (one barrier/tile, lgkm-only drain); P per-wave 16x72.
__global__ __launch_bounds__(256, 2) void attn_kernel(
    const unsigned short* __restrict__ qb, const unsigned short* __restrict__ kb,
    const unsigned short* __restrict__ vt,
    const unsigned long long* __restrict__ mbits,
    unsigned short* __restrict__ ctx) {
  const int h = blockIdx.x, qt = blockIdx.y, b = blockIdx.z;
  const int bh = b * NH + h;
  const int tid = threadIdx.x, lane = tid & 63, wid = tid >> 6;
  const int quad = lane >> 4, c = lane & 15, cx = c & 7;
  const int qw = wid & 1, kh = wid >> 1;
  const int q0 = qt * 128;
  __shared__ __align__(16) unsigned short KV[2][4][4096];   // 64 KB dbuf
  __shared__ __align__(16) unsigned short Pbuf[4][16 * 72];  // 9 KB

  const int qbase = q0 + qw * 64;
  const unsigned short* qp = qb + (size_t)(bh * S_LEN + qbase + c) * DH;
  bf16x8 bq[4][2];
#pragma unroll
  for (int sub = 0; sub < 4; ++sub) {
    bq[sub][0] = *(const bf16x8*)(qp + sub * 16 * DH + quad * 8);
    bq[sub][1] = *(const bf16x8*)(qp + sub * 16 * DH + 32 + quad * 8);
  }

  f32x4 o[4][4] = {};
  float lacc[4] = {0.f, 0.f, 0.f, 0.f};
  const unsigned long long* mq0 =
      mbits + (size_t)(b * S_LEN + qbase + c) * 32 + kh * 16;

  const int srow = lane >> 3;
  const int schk = ((lane & 7) ^ srow) * 8;
  unsigned short* Pw = Pbuf[wid];
  const bool isV = wid >= 2;
  const unsigned short* gK =
      kb + (size_t)(bh * S_LEN + (wid & 1) * 1024 + srow) * DH + schk;
  const unsigned short* gV =
      vt + (size_t)(bh * DH + srow) * S_LEN + (wid - 2) * 1024 + schk;

  // prologue: tile 0 into regs
  uint4 st[8];
  if (!isV) {
#pragma unroll
    for (int i = 0; i < 8; ++i)
      st[i] = *(const uint4*)(gK + (size_t)(i * 8) * DH);
  } else {
#pragma unroll
    for (int i = 0; i < 8; ++i)
      st[i] = *(const uint4*)(gV + (size_t)(i * 8) * S_LEN);
  }

  for (int kt = 0; kt < 1024; kt += 64) {
    const int pb = (kt >> 6) & 1;
    unsigned short* dstp = &KV[pb][wid][0] + lane * 8;
#pragma unroll
    for (int i = 0; i < 8; ++i) *(uint4*)(dstp + i * 512) = st[i];
    __syncthreads();  // lgkm drain only; no outstanding vmem here
    if (kt + 64 < 1024) {
      if (!isV) {
#pragma unroll
        for (int i = 0; i < 8; ++i)
          st[i] = *(const uint4*)(gK + (size_t)(kt + 64 + i * 8) * DH);
      } else {
#pragma unroll
        for (int i = 0; i < 8; ++i)
          st[i] = *(const uint4*)(gV + (size_t)(i * 8) * S_LEN + kt + 64);
      }
    }
    const unsigned short* Ksh = &KV[pb][kh][0];
    const unsigned short* Vsh = &KV[pb][2 + kh][0];

    bf16x8 kf[8];
#pragma unroll
    for (int g = 0; g < 4; ++g) {
      const int rho = g * 16 + c;
      kf[2 * g] = *(const bf16x8*)(&Ksh[rho * 64 + (quad ^ cx) * 8]);
      kf[2 * g + 1] = *(const bf16x8*)(&Ksh[rho * 64 + ((4 + quad) ^ cx) * 8]);
    }

    const int mi = kt >> 6;
    bf16x8 bp[4][2];
#pragma unroll
    for (int sub = 0; sub < 4; ++sub) {
      f32x4 s[4];
#pragma unroll
      for (int g = 0; g < 4; ++g) {
        f32x4 z = {};
        z = mfma16(kf[2 * g], bq[sub][0], z);
        z = mfma16(kf[2 * g + 1], bq[sub][1], z);
        s[g] = z;
      }
      const unsigned long long w64 = mq0[sub * 512 + mi];
      const unsigned int wlo = (unsigned int)w64;
      const unsigned int whi = (unsigned int)(w64 >> 32);
      float lp = 0.f;
#pragma unroll
      for (int g = 0; g < 4; ++g) {
        const unsigned int bits =
            ((g & 2) ? whi : wlo) >> ((g & 1) * 16 + quad * 4);
        f32x4 p;
#pragma unroll
        for (int r = 0; r < 4; ++r) {
          const float e = exp2raw(s[g][r]);
          p[r] = ((bits >> r) & 1u) ? 0.f : e;
          lp += p[r];
        }
        *(bf16x4*)(&Pw[c * 72 + g * 16 + quad * 4]) = cvt4(p);
      }
      lacc[sub] += lp;
      // same-wave LDS round-trip (in-order DS): C-layout -> B-operand
      bp[sub][0] = *(const bf16x8*)(&Pw[c * 72 + quad * 8]);
      bp[sub][1] = *(const bf16x8*)(&Pw[c * 72 + 32 + quad * 8]);
    }

    // ctx^T += V^T · P^T  (V-frag read once, used by all 4 subgroups)
#pragma unroll
    for (int ks = 0; ks < 2; ++ks) {
#pragma unroll
      for (int nt = 0; nt < 4; ++nt) {
        bf16x8 av = *(const bf16x8*)(
            &Vsh[(nt * 16 + c) * 64 + ((ks * 4 + quad) ^ cx) * 8]);
#pragma unroll
        for (int sub = 0; sub < 4; ++sub)
          o[sub][nt] = mfma16(av, bp[sub][ks], o[sub][nt]);
      }
    }
    // no trailing barrier (double buffer)
  }

#pragma unroll
  for (int sub = 0; sub < 4; ++sub) {
    lacc[sub] += __shfl_xor(lacc[sub], 16, 64);
    lacc[sub] += __shfl_xor(lacc[sub], 32, 64);
  }

  __syncthreads();  // all compute reads of KV done before merge reuse
  // merge key-halves via KV region: 8 panels of 16q x 68 floats + l array
  float* mrg = (float*)&KV[0][0][0];
  float* ml = mrg + 8 * 1088;
  if (kh == 1) {
#pragma unroll
    for (int sub = 0; sub < 4; ++sub) {
      float* mo = mrg + (qw * 4 + sub) * 1088;
#pragma unroll
      for (int nt = 0; nt < 4; ++nt)
        *(f32x4*)(mo + c * 68 + nt * 16 + quad * 4) = o[sub][nt];
      if (quad == 0) ml[(qw * 4 + sub) * 16 + c] = lacc[sub];
    }
  }
  __syncthreads();
  if (kh == 0) {
#pragma unroll
    for (int sub = 0; sub < 4; ++sub) {
      const int pp = qw * 4 + sub;
      const float inv = 1.0f / (lacc[sub] + ml[pp * 16 + c]);
      const int q = qbase + sub * 16 + c;
      const float* mo = mrg + pp * 1088;
#pragma unroll
      for (int nt = 0; nt < 4; ++nt) {
        f32x4 ob = *(const f32x4*)(mo + c * 68 + nt * 16 + quad * 4);
        f32x4 rr = (o[sub][nt] + ob) * inv;
        *(bf16x4*)(ctx + (size_t)(b * S_LEN + q) * D_MODEL + h * DH + nt * 16 +
                   quad * 4) = cvt4(rr);
      }
    }
  }
}

extern "C" void kernel_launch(void* const* d_in, const int* in_sizes, int n_in,
                              void* d_out, int out_size, void* d_ws, size_t ws_size,
                              hipStream_t stream) {
  const float* query = (const float*)d_in[0];
  const int* mask = (const int*)d_in[1];
  const float* Wq = (const float*)d_in[2];
  const float* Wk = (const float*)d_in[3];
  const float* Wv = (const float*)d_in[4];
  const float* Wo = (const float*)d_in[5];
  const float* bo = (const float*)d_in[6];
  float* out = (float*)d_out;

  char* ws = (char*)d_ws;
  const size_t MB = 1024 * 1024;
  unsigned short* qbf = (unsigned short*)(ws);           // 8 MB; reused as ctx
  unsigned short* wbf = (unsigned short*)(ws + 8 * MB);  // 8 MB (Wq,Wk,Wv,Wo bf16)
  unsigned short* qb = (unsigned short*)(ws + 16 * MB);  // 8 MB
  unsigned short* kb = (unsigned short*)(ws + 24 * MB);  // 8 MB
  unsigned short* vt = (unsigned short*)(ws + 32 * MB);  // 8 MB
  unsigned long long* mb = (unsigned long long*)(ws + 40 * MB);  // 1 MB
  unsigned short* ctx = qbf;

  prep_kernel<<<32768 + 4096, 256, 0, stream>>>(query, Wq, Wk, Wv, Wo, mask,
                                                qbf, wbf, mb);

  // Q scaled by 1/sqrt(dh) * log2(e): softmax in exp2 domain
  gemm_qkv<<<dim3(3072 / 128, 4096 / 128), 256, 0, stream>>>(
      qbf, wbf, qb, kb, vt, 0.18033688f);

  attn_kernel<<<dim3(NH, S_LEN / 128, 2), 256, 0, stream>>>(qb, kb, vt, mb,
                                                            ctx);

  gemm_out<<<dim3(1024 / 64, 4096 / 128), 256, 0, stream>>>(
      ctx, wbf + 3 * 1048576, out, bo);
}

// Round 9
// 226.352 us; speedup vs baseline: 1.5894x; 1.5894x over previous
//
#include <hip/hip_runtime.h>

#define S_LEN 2048
#define D_MODEL 1024
#define NH 16
#define DH 64

typedef __bf16 bf16x8 __attribute__((ext_vector_type(8)));
typedef __bf16 bf16x4 __attribute__((ext_vector_type(4)));
typedef float f32x4 __attribute__((ext_vector_type(4)));

__device__ __forceinline__ unsigned short f2bf(float f) {
  unsigned int x = __float_as_uint(f);
  x += 0x7fffu + ((x >> 16) & 1u);  // RNE
  return (unsigned short)(x >> 16);
}

__device__ __forceinline__ bf16x4 cvt4(f32x4 v) {
  return __builtin_convertvector(v, bf16x4);
}

__device__ __forceinline__ float exp2raw(float x) {
#if __has_builtin(__builtin_amdgcn_exp2f)
  return __builtin_amdgcn_exp2f(x);
#else
  return exp2f(x);
#endif
}

__device__ __forceinline__ f32x4 mfma16(bf16x8 a, bf16x8 b, f32x4 c) {
  return __builtin_amdgcn_mfma_f32_16x16x32_bf16(a, b, c, 0, 0, 0);
}

__device__ __forceinline__ void gl2lds(const unsigned short* g, unsigned short* l) {
  __builtin_amdgcn_global_load_lds(
      (__attribute__((address_space(1))) void*)g,
      (__attribute__((address_space(3))) void*)l, 16, 0, 0);
}

// ---- fused prep: pack mask bits (blocks 0..32767) + fp32->bf16 convert ----
__global__ __launch_bounds__(256) void prep_kernel(
    const float* __restrict__ q, const float* __restrict__ wq,
    const float* __restrict__ wk, const float* __restrict__ wv,
    const float* __restrict__ wo, const int* __restrict__ mask,
    unsigned short* __restrict__ qbf, unsigned short* __restrict__ wbf,
    unsigned long long* __restrict__ bits) {
  const int bx = blockIdx.x;
  if (bx < 32768) {  // pack mask: 1 bit per (b,q,key), lane i <-> bit i
    int i = bx * 256 + threadIdx.x;
    unsigned long long bal = __ballot(mask[i] != 0);
    if ((threadIdx.x & 63) == 0) bits[i >> 6] = bal;
  } else {  // convert 8 floats per thread
    const long t = (long)(bx - 32768) * 256 + threadIdx.x;
    const float* src;
    unsigned short* dst;
    long e;
    if (t < 524288) { src = q; dst = qbf; e = t * 8; }
    else {
      long u = t - 524288;
      int wi = (int)(u >> 17);
      e = (u & 131071) * 8;
      src = wi == 0 ? wq : wi == 1 ? wk : wi == 2 ? wv : wo;
      dst = wbf + (long)wi * 1048576;
    }
    float4 a = *(const float4*)(src + e);
    float4 b = *(const float4*)(src + e + 4);
    ushort4 p0 = {f2bf(a.x), f2bf(a.y), f2bf(a.z), f2bf(a.w)};
    ushort4 p1 = {f2bf(b.x), f2bf(b.y), f2bf(b.z), f2bf(b.w)};
    *(ushort4*)(dst + e) = p0;
    *(ushort4*)(dst + e + 4) = p1;
  }
}

// ---- fused QKV: C = A(4096x1024) @ [Wq;Wk;Wv](3072x1024)^T; BK=64 (R7) ----
__global__ __launch_bounds__(256) void gemm_qkv(
    const unsigned short* __restrict__ A, const unsigned short* __restrict__ W3,
    unsigned short* __restrict__ qb, unsigned short* __restrict__ kb,
    unsigned short* __restrict__ vt, float qscale) {
  __shared__ unsigned short As[128 * 64];  // 16 KB
  __shared__ unsigned short Bs[128 * 64];
  const int tid = threadIdx.x, lane = tid & 63, wid = tid >> 6;
  const int wm = wid >> 1, wn = wid & 1;
  const int quad = lane >> 4, c = lane & 15, cx = c & 7;
  const int nG = blockIdx.x * 128;
  const int wi = nG >> 10, nn0 = nG & 1023;
  const int m0 = blockIdx.y * 128;
  const unsigned short* Bsrc = W3 + (size_t)wi * 1048576;
  const int srow = lane >> 3;
  const int schk = ((lane & 7) ^ srow) * 8;
  const unsigned short* ag = A + (size_t)(m0 + wid * 32 + srow) * 1024 + schk;
  const unsigned short* bg = Bsrc + (size_t)(nn0 + wid * 32 + srow) * 1024 + schk;
  f32x4 acc[4][4] = {};
  for (int kk = 0; kk < 1024; kk += 64) {
#pragma unroll
    for (int i = 0; i < 4; ++i) {
      gl2lds(ag + (size_t)(i * 8) * 1024 + kk, &As[(wid * 32 + i * 8) * 64]);
      gl2lds(bg + (size_t)(i * 8) * 1024 + kk, &Bs[(wid * 32 + i * 8) * 64]);
    }
    __syncthreads();
#pragma unroll
    for (int kc = 0; kc < 2; ++kc) {
      bf16x8 a[4], b[4];
#pragma unroll
      for (int mt = 0; mt < 4; ++mt)
        a[mt] = *(const bf16x8*)(
            &As[(wm * 64 + mt * 16 + c) * 64 + ((kc * 4 + quad) ^ cx) * 8]);
#pragma unroll
      for (int nt = 0; nt < 4; ++nt)
        b[nt] = *(const bf16x8*)(
            &Bs[(wn * 64 + nt * 16 + c) * 64 + ((kc * 4 + quad) ^ cx) * 8]);
#pragma unroll
      for (int mt = 0; mt < 4; ++mt)
#pragma unroll
        for (int nt = 0; nt < 4; ++nt)
          acc[mt][nt] = mfma16(a[mt], b[nt], acc[mt][nt]);
    }
    __syncthreads();
  }
#pragma unroll
  for (int mt = 0; mt < 4; ++mt) {
#pragma unroll
    for (int nt = 0; nt < 4; ++nt) {
      const int mb = m0 + wm * 64 + mt * 16 + quad * 4;
      const int n = nn0 + wn * 64 + nt * 16 + c;
      const int hh = n >> 6, d = n & 63;
      const int bb = mb >> 11, ss = mb & 2047;
      if (wi == 0) {
#pragma unroll
        for (int r = 0; r < 4; ++r)
          qb[(size_t)((bb * NH + hh) * S_LEN + ss + r) * DH + d] =
              f2bf(acc[mt][nt][r] * qscale);
      } else if (wi == 1) {
#pragma unroll
        for (int r = 0; r < 4; ++r)
          kb[(size_t)((bb * NH + hh) * S_LEN + ss + r) * DH + d] =
              f2bf(acc[mt][nt][r]);
      } else {  // V^T: 4 regs = 4 consecutive s
        *(bf16x4*)(vt + (size_t)((bb * NH + hh) * DH + d) * S_LEN + ss) =
            cvt4(acc[mt][nt]);
      }
    }
  }
}

// ---- O projection: out = ctx(4096x1024) @ Wo^T + bo; BK=64 (R7) ----
__global__ __launch_bounds__(256) void gemm_out(
    const unsigned short* __restrict__ A, const unsigned short* __restrict__ W,
    float* __restrict__ out, const float* __restrict__ bias) {
  __shared__ unsigned short As[128 * 64];  // 16 KB
  __shared__ unsigned short Bs[64 * 64];   // 8 KB
  const int tid = threadIdx.x, lane = tid & 63, wid = tid >> 6;
  const int wm = wid >> 1, wn = wid & 1;
  const int quad = lane >> 4, c = lane & 15, cx = c & 7;
  const int n0 = blockIdx.x * 64, m0 = blockIdx.y * 128;
  const int srow = lane >> 3;
  const int schk = ((lane & 7) ^ srow) * 8;
  const unsigned short* ag = A + (size_t)(m0 + wid * 32 + srow) * 1024 + schk;
  const unsigned short* bg = W + (size_t)(n0 + wid * 16 + srow) * 1024 + schk;
  f32x4 acc[4][2] = {};
  for (int kk = 0; kk < 1024; kk += 64) {
#pragma unroll
    for (int i = 0; i < 4; ++i)
      gl2lds(ag + (size_t)(i * 8) * 1024 + kk, &As[(wid * 32 + i * 8) * 64]);
#pragma unroll
    for (int i = 0; i < 2; ++i)
      gl2lds(bg + (size_t)(i * 8) * 1024 + kk, &Bs[(wid * 16 + i * 8) * 64]);
    __syncthreads();
#pragma unroll
    for (int kc = 0; kc < 2; ++kc) {
      bf16x8 a[4], b[2];
#pragma unroll
      for (int mt = 0; mt < 4; ++mt)
        a[mt] = *(const bf16x8*)(
            &As[(wm * 64 + mt * 16 + c) * 64 + ((kc * 4 + quad) ^ cx) * 8]);
#pragma unroll
      for (int nt = 0; nt < 2; ++nt)
        b[nt] = *(const bf16x8*)(
            &Bs[(wn * 32 + nt * 16 + c) * 64 + ((kc * 4 + quad) ^ cx) * 8]);
#pragma unroll
      for (int mt = 0; mt < 4; ++mt)
#pragma unroll
        for (int nt = 0; nt < 2; ++nt)
          acc[mt][nt] = mfma16(a[mt], b[nt], acc[mt][nt]);
    }
    __syncthreads();
  }
#pragma unroll
  for (int mt = 0; mt < 4; ++mt) {
#pragma unroll
    for (int nt = 0; nt < 2; ++nt) {
      const int mb = m0 + wm * 64 + mt * 16 + quad * 4;
      const int n = n0 + wn * 32 + nt * 16 + c;
      const float bv = bias[n];
#pragma unroll
      for (int r = 0; r < 4; ++r)
        out[(size_t)(mb + r) * D_MODEL + n] = acc[mt][nt][r] + bv;
    }
  }
}

// ---- flash attention: BARRIER-FREE K-loop, wave-private staging ----
// block = (head, 128 q, batch); 4 waves = 2 qwaves(64q) x 2 key-halves.
// Each wave stages its OWN 8KB K + 8KB V tile via global_load_lds and syncs
// only with wave-local s_waitcnt (no __syncthreads in the loop) -> waves
// phase-skew freely, filling VALU/MFMA pipes across waves (anti phase-lock).
// Static-max softmax (scores bounded, fp32-safe); key-half merge = sums.
__global__ __launch_bounds__(256, 2) void attn_kernel(
    const unsigned short* __restrict__ qb, const unsigned short* __restrict__ kb,
    const unsigned short* __restrict__ vt,
    const unsigned long long* __restrict__ mbits,
    unsigned short* __restrict__ ctx) {
  const int h = blockIdx.x, qt = blockIdx.y, b = blockIdx.z;
  const int bh = b * NH + h;
  const int tid = threadIdx.x, lane = tid & 63, wid = tid >> 6;
  const int quad = lane >> 4, c = lane & 15, cx = c & 7;
  const int qw = wid & 1, kh = wid >> 1;
  const int q0 = qt * 128;
  __shared__ __align__(16) unsigned short KVw[4][8192];   // 64 KB: per-wave K|V
  __shared__ __align__(16) unsigned short Pbuf[4][16 * 72];  // 9 KB

  const int qbase = q0 + qw * 64;
  const unsigned short* qp = qb + (size_t)(bh * S_LEN + qbase + c) * DH;
  bf16x8 bq[4][2];
#pragma unroll
  for (int sub = 0; sub < 4; ++sub) {
    bq[sub][0] = *(const bf16x8*)(qp + sub * 16 * DH + quad * 8);
    bq[sub][1] = *(const bf16x8*)(qp + sub * 16 * DH + 32 + quad * 8);
  }

  f32x4 o[4][4] = {};
  float lacc[4] = {0.f, 0.f, 0.f, 0.f};
  const unsigned long long* mq0 =
      mbits + (size_t)(b * S_LEN + qbase + c) * 32 + kh * 16;

  const int srow = lane >> 3;
  const int schk = ((lane & 7) ^ srow) * 8;  // XOR-swizzled 16B chunk
  unsigned short* Kw = KVw[wid];
  unsigned short* Vw = KVw[wid] + 4096;
  unsigned short* Pw = Pbuf[wid];

  const unsigned short* gK =
      kb + (size_t)(bh * S_LEN + kh * 1024 + srow) * DH + schk;
  const unsigned short* gV =
      vt + (size_t)(bh * DH + srow) * S_LEN + kh * 1024 + schk;

  // prologue: stage tile 0 (wave-private)
#pragma unroll
  for (int i = 0; i < 8; ++i) {
    gl2lds(gK + (size_t)(i * 8) * DH, &Kw[i * 512]);
    gl2lds(gV + (size_t)(i * 8) * S_LEN, &Vw[i * 512]);
  }

  for (int kt = 0; kt < 1024; kt += 64) {
    // wave-local: K/V glds (and bq on iter 0) have landed
    asm volatile("s_waitcnt vmcnt(0)" ::: "memory");

    // K-tile fragments -> regs (reused by all 4 q-subgroups)
    bf16x8 kf[8];
#pragma unroll
    for (int g = 0; g < 4; ++g) {
      const int rho = g * 16 + c;
      kf[2 * g] = *(const bf16x8*)(&Kw[rho * 64 + (quad ^ cx) * 8]);
      kf[2 * g + 1] = *(const bf16x8*)(&Kw[rho * 64 + ((4 + quad) ^ cx) * 8]);
    }

    const int mi = kt >> 6;
    bf16x8 bp[4][2];
#pragma unroll
    for (int sub = 0; sub < 4; ++sub) {
      f32x4 s[4];
#pragma unroll
      for (int g = 0; g < 4; ++g) {
        f32x4 z = {};
        z = mfma16(kf[2 * g], bq[sub][0], z);
        z = mfma16(kf[2 * g + 1], bq[sub][1], z);
        s[g] = z;
      }
      const unsigned long long w64 = mq0[sub * 512 + mi];
      const unsigned int wlo = (unsigned int)w64;
      const unsigned int whi = (unsigned int)(w64 >> 32);
      float lp = 0.f;
#pragma unroll
      for (int g = 0; g < 4; ++g) {
        const unsigned int bits =
            ((g & 2) ? whi : wlo) >> ((g & 1) * 16 + quad * 4);
        f32x4 p;
#pragma unroll
        for (int r = 0; r < 4; ++r) {
          const float e = exp2raw(s[g][r]);
          p[r] = ((bits >> r) & 1u) ? 0.f : e;
          lp += p[r];
        }
        *(bf16x4*)(&Pw[c * 72 + g * 16 + quad * 4]) = cvt4(p);
      }
      lacc[sub] += lp;
      // same-wave LDS round-trip (in-order DS): C-layout -> B-operand
      bp[sub][0] = *(const bf16x8*)(&Pw[c * 72 + quad * 8]);
      bp[sub][1] = *(const bf16x8*)(&Pw[c * 72 + 32 + quad * 8]);
    }

    // kf consumed (compiler's lgkm waits before the QK MFMAs retire the
    // ds_reads) -> restage K for t+1 now; in flight across PV compute.
    if (kt + 64 < 1024) {
#pragma unroll
      for (int i = 0; i < 8; ++i)
        gl2lds(gK + (size_t)(kt + 64 + i * 8) * DH, &Kw[i * 512]);
    }

    // ctx^T += V^T · P^T  (V-frag read once, used by all 4 subgroups)
#pragma unroll
    for (int ks = 0; ks < 2; ++ks) {
#pragma unroll
      for (int nt = 0; nt < 4; ++nt) {
        bf16x8 av = *(const bf16x8*)(
            &Vw[(nt * 16 + c) * 64 + ((ks * 4 + quad) ^ cx) * 8]);
#pragma unroll
        for (int sub = 0; sub < 4; ++sub)
          o[sub][nt] = mfma16(av, bp[sub][ks], o[sub][nt]);
      }
    }
    // ensure all V/P ds_reads retired before overwriting Vw (WAR)
    asm volatile("s_waitcnt lgkmcnt(0)" ::: "memory");
    if (kt + 64 < 1024) {
#pragma unroll
      for (int i = 0; i < 8; ++i)
        gl2lds(gV + (size_t)(i * 8) * S_LEN + kt + 64, &Vw[i * 512]);
    }
  }

#pragma unroll
  for (int sub = 0; sub < 4; ++sub) {
    lacc[sub] += __shfl_xor(lacc[sub], 16, 64);
    lacc[sub] += __shfl_xor(lacc[sub], 32, 64);
  }

  __syncthreads();  // all waves done with KVw before merge reuse
  // merge key-halves via KVw region: 8 panels of 16q x 68 floats + l array
  float* mrg = (float*)&KVw[0][0];
  float* ml = mrg + 8 * 1088;
  if (kh == 1) {
#pragma unroll
    for (int sub = 0; sub < 4; ++sub) {
      float* mo = mrg + (qw * 4 + sub) * 1088;
#pragma unroll
      for (int nt = 0; nt < 4; ++nt)
        *(f32x4*)(mo + c * 68 + nt * 16 + quad * 4) = o[sub][nt];
      if (quad == 0) ml[(qw * 4 + sub) * 16 + c] = lacc[sub];
    }
  }
  __syncthreads();
  if (kh == 0) {
#pragma unroll
    for (int sub = 0; sub < 4; ++sub) {
      const int pp = qw * 4 + sub;
      const float inv = 1.0f / (lacc[sub] + ml[pp * 16 + c]);
      const int q = qbase + sub * 16 + c;
      const float* mo = mrg + pp * 1088;
#pragma unroll
      for (int nt = 0; nt < 4; ++nt) {
        f32x4 ob = *(const f32x4*)(mo + c * 68 + nt * 16 + quad * 4);
        f32x4 rr = (o[sub][nt] + ob) * inv;
        *(bf16x4*)(ctx + (size_t)(b * S_LEN + q) * D_MODEL + h * DH + nt * 16 +
                   quad * 4) = cvt4(rr);
      }
    }
  }
}

extern "C" void kernel_launch(void* const* d_in, const int* in_sizes, int n_in,
                              void* d_out, int out_size, void* d_ws, size_t ws_size,
                              hipStream_t stream) {
  const float* query = (const float*)d_in[0];
  const int* mask = (const int*)d_in[1];
  const float* Wq = (const float*)d_in[2];
  const float* Wk = (const float*)d_in[3];
  const float* Wv = (const float*)d_in[4];
  const float* Wo = (const float*)d_in[5];
  const float* bo = (const float*)d_in[6];
  float* out = (float*)d_out;

  char* ws = (char*)d_ws;
  const size_t MB = 1024 * 1024;
  unsigned short* qbf = (unsigned short*)(ws);           // 8 MB; reused as ctx
  unsigned short* wbf = (unsigned short*)(ws + 8 * MB);  // 8 MB (Wq,Wk,Wv,Wo bf16)
  unsigned short* qb = (unsigned short*)(ws + 16 * MB);  // 8 MB
  unsigned short* kb = (unsigned short*)(ws + 24 * MB);  // 8 MB
  unsigned short* vt = (unsigned short*)(ws + 32 * MB);  // 8 MB
  unsigned long long* mb = (unsigned long long*)(ws + 40 * MB);  // 1 MB
  unsigned short* ctx = qbf;

  prep_kernel<<<32768 + 4096, 256, 0, stream>>>(query, Wq, Wk, Wv, Wo, mask,
                                                qbf, wbf, mb);

  // Q scaled by 1/sqrt(dh) * log2(e): softmax in exp2 domain
  gemm_qkv<<<dim3(3072 / 128, 4096 / 128), 256, 0, stream>>>(
      qbf, wbf, qb, kb, vt, 0.18033688f);

  attn_kernel<<<dim3(NH, S_LEN / 128, 2), 256, 0, stream>>>(qb, kb, vt, mb,
                                                            ctx);

  gemm_out<<<dim3(1024 / 64, 4096 / 128), 256, 0, stream>>>(
      ctx, wbf + 3 * 1048576, out, bo);
}

// Round 10
// 224.587 us; speedup vs baseline: 1.6019x; 1.0079x over previous
//
#include <hip/hip_runtime.h>

#define S_LEN 2048
#define D_MODEL 1024
#define NH 16
#define DH 64

typedef __bf16 bf16x8 __attribute__((ext_vector_type(8)));
typedef __bf16 bf16x4 __attribute__((ext_vector_type(4)));
typedef float f32x4 __attribute__((ext_vector_type(4)));

__device__ __forceinline__ unsigned short f2bf(float f) {
  unsigned int x = __float_as_uint(f);
  x += 0x7fffu + ((x >> 16) & 1u);  // RNE
  return (unsigned short)(x >> 16);
}

__device__ __forceinline__ bf16x4 cvt4(f32x4 v) {
  return __builtin_convertvector(v, bf16x4);
}

__device__ __forceinline__ float exp2raw(float x) {
#if __has_builtin(__builtin_amdgcn_exp2f)
  return __builtin_amdgcn_exp2f(x);
#else
  return exp2f(x);
#endif
}

__device__ __forceinline__ f32x4 mfma16(bf16x8 a, bf16x8 b, f32x4 c) {
  return __builtin_amdgcn_mfma_f32_16x16x32_bf16(a, b, c, 0, 0, 0);
}

__device__ __forceinline__ void gl2lds(const unsigned short* g, unsigned short* l) {
  __builtin_amdgcn_global_load_lds(
      (__attribute__((address_space(1))) void*)g,
      (__attribute__((address_space(3))) void*)l, 16, 0, 0);
}

// ---- fused prep: pack mask bits (blocks 0..32767) + fp32->bf16 convert ----
__global__ __launch_bounds__(256) void prep_kernel(
    const float* __restrict__ q, const float* __restrict__ wq,
    const float* __restrict__ wk, const float* __restrict__ wv,
    const float* __restrict__ wo, const int* __restrict__ mask,
    unsigned short* __restrict__ qbf, unsigned short* __restrict__ wbf,
    unsigned long long* __restrict__ bits) {
  const int bx = blockIdx.x;
  if (bx < 32768) {  // pack mask: 1 bit per (b,q,key), lane i <-> bit i
    int i = bx * 256 + threadIdx.x;
    unsigned long long bal = __ballot(mask[i] != 0);
    if ((threadIdx.x & 63) == 0) bits[i >> 6] = bal;
  } else {  // convert 8 floats per thread
    const long t = (long)(bx - 32768) * 256 + threadIdx.x;
    const float* src;
    unsigned short* dst;
    long e;
    if (t < 524288) { src = q; dst = qbf; e = t * 8; }
    else {
      long u = t - 524288;
      int wi = (int)(u >> 17);
      e = (u & 131071) * 8;
      src = wi == 0 ? wq : wi == 1 ? wk : wi == 2 ? wv : wo;
      dst = wbf + (long)wi * 1048576;
    }
    float4 a = *(const float4*)(src + e);
    float4 b = *(const float4*)(src + e + 4);
    ushort4 p0 = {f2bf(a.x), f2bf(a.y), f2bf(a.z), f2bf(a.w)};
    ushort4 p1 = {f2bf(b.x), f2bf(b.y), f2bf(b.z), f2bf(b.w)};
    *(ushort4*)(dst + e) = p0;
    *(ushort4*)(dst + e + 4) = p1;
  }
}

// ---- fused QKV: C = A(4096x1024) @ [Wq;Wk;Wv](3072x1024)^T; BK=64 ----
// wi<2 (Q,K): MFMA operands SWAPPED -> C^T: reg r indexes n (4 consecutive d)
// -> packed b64 stores. wi==2 (V): original orientation, b64 V^T stores.
__global__ __launch_bounds__(256) void gemm_qkv(
    const unsigned short* __restrict__ A, const unsigned short* __restrict__ W3,
    unsigned short* __restrict__ qb, unsigned short* __restrict__ kb,
    unsigned short* __restrict__ vt, float qscale) {
  __shared__ unsigned short As[128 * 64];  // 16 KB
  __shared__ unsigned short Bs[128 * 64];
  const int tid = threadIdx.x, lane = tid & 63, wid = tid >> 6;
  const int wm = wid >> 1, wn = wid & 1;
  const int quad = lane >> 4, c = lane & 15, cx = c & 7;
  const int nG = blockIdx.x * 128;
  const int wi = nG >> 10, nn0 = nG & 1023;
  const int m0 = blockIdx.y * 128;
  const unsigned short* Bsrc = W3 + (size_t)wi * 1048576;
  const int srow = lane >> 3;
  const int schk = ((lane & 7) ^ srow) * 8;
  const unsigned short* ag = A + (size_t)(m0 + wid * 32 + srow) * 1024 + schk;
  const unsigned short* bg = Bsrc + (size_t)(nn0 + wid * 32 + srow) * 1024 + schk;
  f32x4 acc[4][4] = {};
  if (wi < 2) {  // ---- swapped-operand path (Q, K) ----
    for (int kk = 0; kk < 1024; kk += 64) {
#pragma unroll
      for (int i = 0; i < 4; ++i) {
        gl2lds(ag + (size_t)(i * 8) * 1024 + kk, &As[(wid * 32 + i * 8) * 64]);
        gl2lds(bg + (size_t)(i * 8) * 1024 + kk, &Bs[(wid * 32 + i * 8) * 64]);
      }
      __syncthreads();
#pragma unroll
      for (int kc = 0; kc < 2; ++kc) {
        bf16x8 a[4], b[4];
#pragma unroll
        for (int mt = 0; mt < 4; ++mt)
          a[mt] = *(const bf16x8*)(
              &As[(wm * 64 + mt * 16 + c) * 64 + ((kc * 4 + quad) ^ cx) * 8]);
#pragma unroll
        for (int nt = 0; nt < 4; ++nt)
          b[nt] = *(const bf16x8*)(
              &Bs[(wn * 64 + nt * 16 + c) * 64 + ((kc * 4 + quad) ^ cx) * 8]);
#pragma unroll
        for (int mt = 0; mt < 4; ++mt)
#pragma unroll
          for (int nt = 0; nt < 4; ++nt)
            acc[mt][nt] = mfma16(b[nt], a[mt], acc[mt][nt]);  // swapped
      }
      __syncthreads();
    }
    unsigned short* dst = (wi == 0) ? qb : kb;
    const float sc = (wi == 0) ? qscale : 1.0f;
#pragma unroll
    for (int mt = 0; mt < 4; ++mt) {
#pragma unroll
      for (int nt = 0; nt < 4; ++nt) {
        const int ss = m0 + wm * 64 + mt * 16 + c;   // s (c-side)
        const int nS = nn0 + wn * 64 + nt * 16 + quad * 4;  // n (quad-side)
        const int hh = nS >> 6, d0 = nS & 63;
        const int bb = ss >> 11, sl = ss & 2047;
        f32x4 v = acc[mt][nt] * sc;
        *(bf16x4*)(dst + (size_t)((bb * NH + hh) * S_LEN + sl) * DH + d0) =
            cvt4(v);
      }
    }
  } else {  // ---- original orientation (V -> V^T) ----
    for (int kk = 0; kk < 1024; kk += 64) {
#pragma unroll
      for (int i = 0; i < 4; ++i) {
        gl2lds(ag + (size_t)(i * 8) * 1024 + kk, &As[(wid * 32 + i * 8) * 64]);
        gl2lds(bg + (size_t)(i * 8) * 1024 + kk, &Bs[(wid * 32 + i * 8) * 64]);
      }
      __syncthreads();
#pragma unroll
      for (int kc = 0; kc < 2; ++kc) {
        bf16x8 a[4], b[4];
#pragma unroll
        for (int mt = 0; mt < 4; ++mt)
          a[mt] = *(const bf16x8*)(
              &As[(wm * 64 + mt * 16 + c) * 64 + ((kc * 4 + quad) ^ cx) * 8]);
#pragma unroll
        for (int nt = 0; nt < 4; ++nt)
          b[nt] = *(const bf16x8*)(
              &Bs[(wn * 64 + nt * 16 + c) * 64 + ((kc * 4 + quad) ^ cx) * 8]);
#pragma unroll
        for (int mt = 0; mt < 4; ++mt)
#pragma unroll
          for (int nt = 0; nt < 4; ++nt)
            acc[mt][nt] = mfma16(a[mt], b[nt], acc[mt][nt]);
      }
      __syncthreads();
    }
#pragma unroll
    for (int mt = 0; mt < 4; ++mt) {
#pragma unroll
      for (int nt = 0; nt < 4; ++nt) {
        const int mb = m0 + wm * 64 + mt * 16 + quad * 4;
        const int n = nn0 + wn * 64 + nt * 16 + c;
        const int hh = n >> 6, d = n & 63;
        const int bb = mb >> 11, ss = mb & 2047;
        *(bf16x4*)(vt + (size_t)((bb * NH + hh) * DH + d) * S_LEN + ss) =
            cvt4(acc[mt][nt]);
      }
    }
  }
}

// ---- O projection, swapped operands -> float4 stores; BK=64 ----
__global__ __launch_bounds__(256) void gemm_out(
    const unsigned short* __restrict__ A, const unsigned short* __restrict__ W,
    float* __restrict__ out, const float* __restrict__ bias) {
  __shared__ unsigned short As[128 * 64];  // 16 KB
  __shared__ unsigned short Bs[64 * 64];   // 8 KB
  const int tid = threadIdx.x, lane = tid & 63, wid = tid >> 6;
  const int wm = wid >> 1, wn = wid & 1;
  const int quad = lane >> 4, c = lane & 15, cx = c & 7;
  const int n0 = blockIdx.x * 64, m0 = blockIdx.y * 128;
  const int srow = lane >> 3;
  const int schk = ((lane & 7) ^ srow) * 8;
  const unsigned short* ag = A + (size_t)(m0 + wid * 32 + srow) * 1024 + schk;
  const unsigned short* bg = W + (size_t)(n0 + wid * 16 + srow) * 1024 + schk;
  f32x4 acc[4][2] = {};
  for (int kk = 0; kk < 1024; kk += 64) {
#pragma unroll
    for (int i = 0; i < 4; ++i)
      gl2lds(ag + (size_t)(i * 8) * 1024 + kk, &As[(wid * 32 + i * 8) * 64]);
#pragma unroll
    for (int i = 0; i < 2; ++i)
      gl2lds(bg + (size_t)(i * 8) * 1024 + kk, &Bs[(wid * 16 + i * 8) * 64]);
    __syncthreads();
#pragma unroll
    for (int kc = 0; kc < 2; ++kc) {
      bf16x8 a[4], b[2];
#pragma unroll
      for (int mt = 0; mt < 4; ++mt)
        a[mt] = *(const bf16x8*)(
            &As[(wm * 64 + mt * 16 + c) * 64 + ((kc * 4 + quad) ^ cx) * 8]);
#pragma unroll
      for (int nt = 0; nt < 2; ++nt)
        b[nt] = *(const bf16x8*)(
            &Bs[(wn * 32 + nt * 16 + c) * 64 + ((kc * 4 + quad) ^ cx) * 8]);
#pragma unroll
      for (int mt = 0; mt < 4; ++mt)
#pragma unroll
        for (int nt = 0; nt < 2; ++nt)
          acc[mt][nt] = mfma16(b[nt], a[mt], acc[mt][nt]);  // swapped
    }
    __syncthreads();
  }
#pragma unroll
  for (int mt = 0; mt < 4; ++mt) {
#pragma unroll
    for (int nt = 0; nt < 2; ++nt) {
      const int m = m0 + wm * 64 + mt * 16 + c;           // m (c-side)
      const int n = n0 + wn * 32 + nt * 16 + quad * 4;    // n (quad-side)
      f32x4 bv = *(const f32x4*)(bias + n);
      f32x4 r = acc[mt][nt] + bv;
      *(f32x4*)(out + (size_t)m * D_MODEL + n) = r;
    }
  }
}

// ---- flash attention: barrier-free K-loop, wave-private staging (R9) ----
// + exact split waits: prologue all-K-then-all-V; vmcnt(8) drains K before
// kf reads; vmcnt(8/0) drains V before PV reads (K(t+1) stays in flight).
__global__ __launch_bounds__(256, 2) void attn_kernel(
    const unsigned short* __restrict__ qb, const unsigned short* __restrict__ kb,
    const unsigned short* __restrict__ vt,
    const unsigned long long* __restrict__ mbits,
    unsigned short* __restrict__ ctx) {
  const int h = blockIdx.x, qt = blockIdx.y, b = blockIdx.z;
  const int bh = b * NH + h;
  const int tid = threadIdx.x, lane = tid & 63, wid = tid >> 6;
  const int quad = lane >> 4, c = lane & 15, cx = c & 7;
  const int qw = wid & 1, kh = wid >> 1;
  const int q0 = qt * 128;
  __shared__ __align__(16) unsigned short KVw[4][8192];   // 64 KB: per-wave K|V
  __shared__ __align__(16) unsigned short Pbuf[4][16 * 72];  // 9 KB

  const int qbase = q0 + qw * 64;
  const unsigned short* qp = qb + (size_t)(bh * S_LEN + qbase + c) * DH;
  bf16x8 bq[4][2];
#pragma unroll
  for (int sub = 0; sub < 4; ++sub) {
    bq[sub][0] = *(const bf16x8*)(qp + sub * 16 * DH + quad * 8);
    bq[sub][1] = *(const bf16x8*)(qp + sub * 16 * DH + 32 + quad * 8);
  }

  f32x4 o[4][4] = {};
  float lacc[4] = {0.f, 0.f, 0.f, 0.f};
  const unsigned long long* mq0 =
      mbits + (size_t)(b * S_LEN + qbase + c) * 32 + kh * 16;

  const int srow = lane >> 3;
  const int schk = ((lane & 7) ^ srow) * 8;  // XOR-swizzled 16B chunk
  unsigned short* Kw = KVw[wid];
  unsigned short* Vw = KVw[wid] + 4096;
  unsigned short* Pw = Pbuf[wid];

  const unsigned short* gK =
      kb + (size_t)(bh * S_LEN + kh * 1024 + srow) * DH + schk;
  const unsigned short* gV =
      vt + (size_t)(bh * DH + srow) * S_LEN + kh * 1024 + schk;

  // prologue: all K first, then all V (so vmcnt(8) == "K drained")
#pragma unroll
  for (int i = 0; i < 8; ++i) gl2lds(gK + (size_t)(i * 8) * DH, &Kw[i * 512]);
#pragma unroll
  for (int i = 0; i < 8; ++i)
    gl2lds(gV + (size_t)(i * 8) * S_LEN, &Vw[i * 512]);

  for (int kt = 0; kt < 1024; kt += 64) {
    // drain K (oldest); V's 8 loads may stay in flight
    asm volatile("s_waitcnt vmcnt(8)" ::: "memory");

    bf16x8 kf[8];
#pragma unroll
    for (int g = 0; g < 4; ++g) {
      const int rho = g * 16 + c;
      kf[2 * g] = *(const bf16x8*)(&Kw[rho * 64 + (quad ^ cx) * 8]);
      kf[2 * g + 1] = *(const bf16x8*)(&Kw[rho * 64 + ((4 + quad) ^ cx) * 8]);
    }

    const int mi = kt >> 6;
    bf16x8 bp[4][2];
#pragma unroll
    for (int sub = 0; sub < 4; ++sub) {
      f32x4 s[4];
#pragma unroll
      for (int g = 0; g < 4; ++g) {
        f32x4 z = {};
        z = mfma16(kf[2 * g], bq[sub][0], z);
        z = mfma16(kf[2 * g + 1], bq[sub][1], z);
        s[g] = z;
      }
      const unsigned long long w64 = mq0[sub * 512 + mi];
      const unsigned int wlo = (unsigned int)w64;
      const unsigned int whi = (unsigned int)(w64 >> 32);
      float lp = 0.f;
#pragma unroll
      for (int g = 0; g < 4; ++g) {
        const unsigned int bits =
            ((g & 2) ? whi : wlo) >> ((g & 1) * 16 + quad * 4);
        f32x4 p;
#pragma unroll
        for (int r = 0; r < 4; ++r) {
          const float e = exp2raw(s[g][r]);
          p[r] = ((bits >> r) & 1u) ? 0.f : e;
          lp += p[r];
        }
        *(bf16x4*)(&Pw[c * 72 + g * 16 + quad * 4]) = cvt4(p);
      }
      lacc[sub] += lp;
      bp[sub][0] = *(const bf16x8*)(&Pw[c * 72 + quad * 8]);
      bp[sub][1] = *(const bf16x8*)(&Pw[c * 72 + 32 + quad * 8]);
    }

    // restage K for t+1 (in flight across PV)
    if (kt + 64 < 1024) {
#pragma unroll
      for (int i = 0; i < 8; ++i)
        gl2lds(gK + (size_t)(kt + 64 + i * 8) * DH, &Kw[i * 512]);
      asm volatile("s_waitcnt vmcnt(8)" ::: "memory");  // drain V(t)
    } else {
      asm volatile("s_waitcnt vmcnt(0)" ::: "memory");  // last tile
    }

#pragma unroll
    for (int ks = 0; ks < 2; ++ks) {
#pragma unroll
      for (int nt = 0; nt < 4; ++nt) {
        bf16x8 av = *(const bf16x8*)(
            &Vw[(nt * 16 + c) * 64 + ((ks * 4 + quad) ^ cx) * 8]);
#pragma unroll
        for (int sub = 0; sub < 4; ++sub)
          o[sub][nt] = mfma16(av, bp[sub][ks], o[sub][nt]);
      }
    }
    asm volatile("s_waitcnt lgkmcnt(0)" ::: "memory");  // Vw WAR
    if (kt + 64 < 1024) {
#pragma unroll
      for (int i = 0; i < 8; ++i)
        gl2lds(gV + (size_t)(i * 8) * S_LEN + kt + 64, &Vw[i * 512]);
    }
  }

#pragma unroll
  for (int sub = 0; sub < 4; ++sub) {
    lacc[sub] += __shfl_xor(lacc[sub], 16, 64);
    lacc[sub] += __shfl_xor(lacc[sub], 32, 64);
  }

  __syncthreads();  // all waves done with KVw before merge reuse
  float* mrg = (float*)&KVw[0][0];
  float* ml = mrg + 8 * 1088;
  if (kh == 1) {
#pragma unroll
    for (int sub = 0; sub < 4; ++sub) {
      float* mo = mrg + (qw * 4 + sub) * 1088;
#pragma unroll
      for (int nt = 0; nt < 4; ++nt)
        *(f32x4*)(mo + c * 68 + nt * 16 + quad * 4) = o[sub][nt];
      if (quad == 0) ml[(qw * 4 + sub) * 16 + c] = lacc[sub];
    }
  }
  __syncthreads();
  if (kh == 0) {
#pragma unroll
    for (int sub = 0; sub < 4; ++sub) {
      const int pp = qw * 4 + sub;
      const float inv = 1.0f / (lacc[sub] + ml[pp * 16 + c]);
      const int q = qbase + sub * 16 + c;
      const float* mo = mrg + pp * 1088;
#pragma unroll
      for (int nt = 0; nt < 4; ++nt) {
        f32x4 ob = *(const f32x4*)(mo + c * 68 + nt * 16 + quad * 4);
        f32x4 rr = (o[sub][nt] + ob) * inv;
        *(bf16x4*)(ctx + (size_t)(b * S_LEN + q) * D_MODEL + h * DH + nt * 16 +
                   quad * 4) = cvt4(rr);
      }
    }
  }
}

extern "C" void kernel_launch(void* const* d_in, const int* in_sizes, int n_in,
                              void* d_out, int out_size, void* d_ws, size_t ws_size,
                              hipStream_t stream) {
  const float* query = (const float*)d_in[0];
  const int* mask = (const int*)d_in[1];
  const float* Wq = (const float*)d_in[2];
  const float* Wk = (const float*)d_in[3];
  const float* Wv = (const float*)d_in[4];
  const float* Wo = (const float*)d_in[5];
  const float* bo = (const float*)d_in[6];
  float* out = (float*)d_out;

  char* ws = (char*)d_ws;
  const size_t MB = 1024 * 1024;
  unsigned short* qbf = (unsigned short*)(ws);           // 8 MB; reused as ctx
  unsigned short* wbf = (unsigned short*)(ws + 8 * MB);  // 8 MB (Wq,Wk,Wv,Wo bf16)
  unsigned short* qb = (unsigned short*)(ws + 16 * MB);  // 8 MB
  unsigned short* kb = (unsigned short*)(ws + 24 * MB);  // 8 MB
  unsigned short* vt = (unsigned short*)(ws + 32 * MB);  // 8 MB
  unsigned long long* mb = (unsigned long long*)(ws + 40 * MB);  // 1 MB
  unsigned short* ctx = qbf;

  prep_kernel<<<32768 + 4096, 256, 0, stream>>>(query, Wq, Wk, Wv, Wo, mask,
                                                qbf, wbf, mb);

  // Q scaled by 1/sqrt(dh) * log2(e): softmax in exp2 domain
  gemm_qkv<<<dim3(3072 / 128, 4096 / 128), 256, 0, stream>>>(
      qbf, wbf, qb, kb, vt, 0.18033688f);

  attn_kernel<<<dim3(NH, S_LEN / 128, 2), 256, 0, stream>>>(qb, kb, vt, mb,
                                                            ctx);

  gemm_out<<<dim3(1024 / 64, 4096 / 128), 256, 0, stream>>>(
      ctx, wbf + 3 * 1048576, out, bo);
}